// Round 10
// baseline (370.485 us; speedup 1.0000x reference)
//
#include <hip/hip_runtime.h>
#include <cmath>

// ---------------------------------------------------------------------------
// SConvNetBlock: LN1 -> SiLU -> complex-decay scan -> *sc_lin -> +res
//                -> LN2 -> FFN(GEMM+SiLU+GEMM) -> +res
// Round-10: 5 launches.
//  * prep = cast(w1) + cast(w2) + ln1_stats (grid-partitioned, r9).
//  * scan_partial: vectorized column scan, CHUNKS=128 (r6, validated).
//  * scan_final: full-row blocks; inline prefix fold from e (combine
//    deleted, fold parallel across 512 blocks); computes x2 AND fused
//    LN2 -> h2 fp16 via per-row block reduction (r4 validated reduction).
//    ln_kernel DELETED (-1 launch, -48MB traffic).
//  * GEMM1 32x32x16 / GEMM2 16x16x32, m97 2-barrier 128x128, XCD-chunked
//    (byte-identical to r9, best measured cell).
// ---------------------------------------------------------------------------

#define DIMD 1024
#define FFD  4096
#define BATCH 4
#define SEQL 2048
#define MROWS (BATCH*SEQL)      // 8192
#define EPSF 1e-5f
#define CHUNKS2 128
#define CLEN2 (SEQL/CHUNKS2)    // 16
#define CAST_BLKS (FFD*DIMD/1024)   // 4096 blocks per weight cast

typedef __attribute__((ext_vector_type(8)))  _Float16 half8;
typedef __attribute__((ext_vector_type(4)))  _Float16 half4;
typedef __attribute__((ext_vector_type(4)))  float    floatx4;
typedef __attribute__((ext_vector_type(16))) float    floatx16;

// ---- workspace layout (bytes) ----
#define ST_OFF   0u                       // st  float2 [8192]         64 KB
#define E_OFF    1048576u                 // e   float2 [4][128][1024]   4 MB
#define H2_OFF   35651584u                // h2  fp16 [8192][1024]     16 MB
#define W1H_OFF  52428800u                // w1h fp16 [4096][1024]      8 MB
#define W2H_OFF  60817408u                // w2h fp16 [1024][4096]      8 MB
#define Y1_OFF   69206016u                // y1  fp16 [8192][4096]     64 MB

__device__ __forceinline__ void load_lds16(const _Float16* g, _Float16* l) {
    __builtin_amdgcn_global_load_lds(
        (const __attribute__((address_space(1))) unsigned int*)g,
        (__attribute__((address_space(3))) unsigned int*)l,
        16, 0, 0);
}

// ---------------------------------------------------------------------------
// prep: blocks [0,8192) = ln1 stats rows; [8192,12288) = cast w1;
//       [12288,16384) = cast w2.
// ---------------------------------------------------------------------------
__global__ __launch_bounds__(256)
void prep(const float* __restrict__ x, float2* __restrict__ st,
          const float* __restrict__ w1, _Float16* __restrict__ w1h,
          const float* __restrict__ w2, _Float16* __restrict__ w2h) {
    const int bid = blockIdx.x;
    const int tid = threadIdx.x;
    if (bid < MROWS) {
        const size_t row = bid;
        float4 v = *(const float4*)(x + row * DIMD + tid * 4);
        float s = (v.x + v.y) + (v.z + v.w);
        float q = (v.x * v.x + v.y * v.y) + (v.z * v.z + v.w * v.w);
        #pragma unroll
        for (int off = 32; off; off >>= 1) {
            s += __shfl_down(s, off, 64);
            q += __shfl_down(q, off, 64);
        }
        __shared__ float red[8];
        if (!(tid & 63)) { red[tid >> 6] = s; red[4 + (tid >> 6)] = q; }
        __syncthreads();
        if (tid == 0) {
            s = (red[0] + red[1]) + (red[2] + red[3]);
            q = (red[4] + red[5]) + (red[6] + red[7]);
            const float mu = s * (1.f / DIMD);
            const float rs = rsqrtf(q * (1.f / DIMD) - mu * mu + EPSF);
            st[row] = make_float2(mu, rs);
        }
    } else {
        int b = bid - MROWS;
        const float* src;
        _Float16* dst;
        if (b < CAST_BLKS) { src = w1; dst = w1h; }
        else { b -= CAST_BLKS; src = w2; dst = w2h; }
        int i = (b * 256 + tid) * 4;
        float4 v = *(const float4*)(src + i);
        half4 o;
        o.x = (_Float16)v.x; o.y = (_Float16)v.y;
        o.z = (_Float16)v.z; o.w = (_Float16)v.w;
        *(half4*)(dst + i) = o;
    }
}

__device__ __forceinline__ void get_p(const float* pre, const float* pim, int d,
                                      float& pr, float& pi) {
    float re = pre[d], im = pim[d];
    float r = sqrtf(re * re + im * im);
    float t = tanhf(r) / fmaxf(r, 1e-30f);
    pr = re * t; pi = im * t;
}

// per-chunk local scan (zero init), fused LN1+SiLU recompute, float4 over d.
// block = (chunk c, batch b); thread owns d = 4*tid .. 4*tid+3.  (r6 kernel)
__global__ __launch_bounds__(256)
void scan_partial(const float* __restrict__ x, const float2* __restrict__ st,
                  const float* __restrict__ lw, const float* __restrict__ lb,
                  const float* __restrict__ pre, const float* __restrict__ pim,
                  float2* __restrict__ e) {
    const int tid = threadIdx.x;
    const int c = blockIdx.x;
    const int bb = blockIdx.y;
    const int d0 = tid * 4;
    float pr[4], pi[4];
    #pragma unroll
    for (int k = 0; k < 4; ++k) get_p(pre, pim, d0 + k, pr[k], pi[k]);
    const float4 wv = *(const float4*)(lw + d0);
    const float4 bv = *(const float4*)(lb + d0);
    const float wa[4] = {wv.x, wv.y, wv.z, wv.w};
    const float ba[4] = {bv.x, bv.y, bv.z, bv.w};
    const size_t row0 = (size_t)bb * SEQL + (size_t)c * CLEN2;
    float sr[4] = {0.f, 0.f, 0.f, 0.f}, si[4] = {0.f, 0.f, 0.f, 0.f};
    #pragma unroll
    for (int j = 0; j < CLEN2; ++j) {
        float4 v = *(const float4*)(x + (row0 + j) * DIMD + d0);
        float2 sj = st[row0 + j];
        const float xa[4] = {v.x, v.y, v.z, v.w};
        #pragma unroll
        for (int k = 0; k < 4; ++k) {
            float o = (xa[k] - sj.x) * sj.y * wa[k] + ba[k];
            float h = o / (1.f + __expf(-o));
            float nr = pr[k] * sr[k] - pi[k] * si[k] + h;
            float ni = pr[k] * si[k] + pi[k] * sr[k];
            sr[k] = nr; si[k] = ni;
        }
    }
    float2* ep = e + ((size_t)bb * CHUNKS2 + c) * DIMD + d0;
    #pragma unroll
    for (int k = 0; k < 4; ++k) ep[k] = make_float2(sr[k], si[k]);
}

// block-wide (256 thr) sum of (s,q), broadcast; red = __shared__ [2][8];
// buf = row parity (one __syncthreads per row).  (r4 validated)
__device__ __forceinline__ void block_red2(float& s, float& q, float (*red)[8],
                                           int tid, int buf) {
    #pragma unroll
    for (int off = 32; off; off >>= 1) {
        s += __shfl_down(s, off, 64);
        q += __shfl_down(q, off, 64);
    }
    if (!(tid & 63)) { red[buf][tid >> 6] = s; red[buf][4 + (tid >> 6)] = q; }
    __syncthreads();
    s = (red[buf][0] + red[buf][1]) + (red[buf][2] + red[buf][3]);
    q = (red[buf][4] + red[buf][5]) + (red[buf][6] + red[buf][7]);
}

// final scan, full-row blocks: inline prefix fold from e, x2 = x + sc*Re(c),
// fused LN2 -> h2 fp16 via per-row block reduction.  ln_kernel deleted.
__global__ __launch_bounds__(256)
void scan_final(const float* __restrict__ x, const float2* __restrict__ st,
                const float* __restrict__ l1w, const float* __restrict__ l1b,
                const float* __restrict__ l2w, const float* __restrict__ l2b,
                const float* __restrict__ pre, const float* __restrict__ pim,
                const float* __restrict__ sc, const float* __restrict__ lre,
                const float* __restrict__ lim, const float2* __restrict__ e,
                float* __restrict__ x2, _Float16* __restrict__ h2) {
    const int tid = threadIdx.x;
    const int c = blockIdx.x;
    const int bb = blockIdx.y;
    const int d0 = tid * 4;
    float pr[4], pi[4];
    #pragma unroll
    for (int k = 0; k < 4; ++k) get_p(pre, pim, d0 + k, pr[k], pi[k]);
    const float4 w1v = *(const float4*)(l1w + d0);
    const float4 b1v = *(const float4*)(l1b + d0);
    const float4 w2v = *(const float4*)(l2w + d0);
    const float4 b2v = *(const float4*)(l2b + d0);
    const float4 scv = *(const float4*)(sc + d0);
    const float w1a[4] = {w1v.x, w1v.y, w1v.z, w1v.w};
    const float b1a[4] = {b1v.x, b1v.y, b1v.z, b1v.w};
    const float w2a[4] = {w2v.x, w2v.y, w2v.z, w2v.w};
    const float b2a[4] = {b2v.x, b2v.y, b2v.z, b2v.w};
    const float sca[4] = {scv.x, scv.y, scv.z, scv.w};

    // q = p^CLEN2 = p^16 via 4 squarings (same sequence as old combine)
    float qr[4], qi[4];
    #pragma unroll
    for (int k = 0; k < 4; ++k) { qr[k] = pr[k]; qi[k] = pi[k]; }
    #pragma unroll
    for (int s = 0; s < 4; ++s)
        #pragma unroll
        for (int k = 0; k < 4; ++k) {
            float nr = qr[k] * qr[k] - qi[k] * qi[k];
            float ni = 2.f * qr[k] * qi[k];
            qr[k] = nr; qi[k] = ni;
        }

    // incoming state: fold chunks [0, c)  (parallel across blocks)
    float sr[4], si[4];
    #pragma unroll
    for (int k = 0; k < 4; ++k) { sr[k] = lre[d0 + k]; si[k] = lim[d0 + k]; }
    const float2* ep = e + (size_t)bb * CHUNKS2 * DIMD + d0;
    for (int cc = 0; cc < c; ++cc) {
        #pragma unroll
        for (int k = 0; k < 4; ++k) {
            float2 ec = ep[(size_t)cc * DIMD + k];
            float nr = qr[k] * sr[k] - qi[k] * si[k] + ec.x;
            float ni = qr[k] * si[k] + qi[k] * sr[k] + ec.y;
            sr[k] = nr; si[k] = ni;
        }
    }

    const size_t row0 = (size_t)bb * SEQL + (size_t)c * CLEN2;
    __shared__ float red[2][8];
    #pragma unroll
    for (int j = 0; j < CLEN2; ++j) {
        float4 v = *(const float4*)(x + (row0 + j) * DIMD + d0);
        float2 sj = st[row0 + j];
        const float xa[4] = {v.x, v.y, v.z, v.w};
        float x2v[4];
        #pragma unroll
        for (int k = 0; k < 4; ++k) {
            float o = (xa[k] - sj.x) * sj.y * w1a[k] + b1a[k];
            float h = o / (1.f + __expf(-o));
            float nr = pr[k] * sr[k] - pi[k] * si[k] + h;
            float ni = pr[k] * si[k] + pi[k] * sr[k];
            sr[k] = nr; si[k] = ni;
            x2v[k] = xa[k] + sca[k] * nr;
        }
        float4 xo = {x2v[0], x2v[1], x2v[2], x2v[3]};
        *(float4*)(x2 + (row0 + j) * DIMD + d0) = xo;
        // fused LN2 on the in-register x2 row
        float s = (x2v[0] + x2v[1]) + (x2v[2] + x2v[3]);
        float q = (x2v[0] * x2v[0] + x2v[1] * x2v[1]) +
                  (x2v[2] * x2v[2] + x2v[3] * x2v[3]);
        block_red2(s, q, red, tid, j & 1);
        const float mu = s * (1.f / DIMD);
        const float rs = rsqrtf(q * (1.f / DIMD) - mu * mu + EPSF);
        half4 hv;
        hv.x = (_Float16)((x2v[0] - mu) * rs * w2a[0] + b2a[0]);
        hv.y = (_Float16)((x2v[1] - mu) * rs * w2a[1] + b2a[1]);
        hv.z = (_Float16)((x2v[2] - mu) * rs * w2a[2] + b2a[2]);
        hv.w = (_Float16)((x2v[3] - mu) * rs * w2a[3] + b2a[3]);
        *(half4*)(h2 + (row0 + j) * DIMD + d0) = hv;
    }
}

// ---------------------------------------------------------------------------
// GEMM1: 32x32x16 MFMA, m97 2-barrier 128x128 tile, 32KB LDS, XCD-chunked.
// out_h = fp16(silu(C + bias)).   (byte-identical to r9)
// ---------------------------------------------------------------------------
#define GBM 128
#define GBN 128
#define GBK 64

template<int NCOLS>
__global__ __launch_bounds__(256)
void gemm1_32(const _Float16* __restrict__ A, const _Float16* __restrict__ W,
              const float* __restrict__ bias, _Float16* __restrict__ out_h,
              int N, int K) {
    __shared__ _Float16 As[GBM * GBK];
    __shared__ _Float16 Bs[GBN * GBK];
    const int tid  = threadIdx.x;
    const int lane = tid & 63;
    const int wave = tid >> 6;
    const int wm = (wave >> 1) * 64;
    const int wn = (wave & 1) * 64;
    const int n  = blockIdx.y * gridDim.x + blockIdx.x;
    const int xc = n & 7, ii = n >> 3;
    const size_t m0 = (size_t)(xc + ((ii / NCOLS) << 3)) * GBM;
    const size_t n0 = (size_t)(ii % NCOLS) * GBN;
    const int r32 = lane & 31;
    const int kg  = lane >> 5;

    const int srow = wave * 32 + (lane >> 3);
    const int ccp  = ((lane & 7) ^ (lane >> 3)) * 8;
    const _Float16* ag = A + (m0 + srow) * (size_t)K + ccp;
    const _Float16* wg = W + (n0 + srow) * (size_t)K + ccp;
    _Float16* asl = &As[(wave * 32) * GBK];
    _Float16* bsl = &Bs[(wave * 32) * GBK];

    floatx16 acc[2][2] = {};

    for (int k0 = 0; k0 < K; k0 += GBK) {
        #pragma unroll
        for (int t = 0; t < 4; ++t) {
            load_lds16(ag + k0 + (size_t)(t * 8) * K, asl + t * 8 * GBK);
            load_lds16(wg + k0 + (size_t)(t * 8) * K, bsl + t * 8 * GBK);
        }
        __syncthreads();
        #pragma unroll
        for (int ks = 0; ks < 4; ++ks) {
            const int slot = (((ks << 1) | kg) ^ (r32 & 7)) * 8;
            half8 af0 = *(const half8*)(&As[(wm +      r32) * GBK + slot]);
            half8 af1 = *(const half8*)(&As[(wm + 32 + r32) * GBK + slot]);
            half8 bf0 = *(const half8*)(&Bs[(wn +      r32) * GBK + slot]);
            half8 bf1 = *(const half8*)(&Bs[(wn + 32 + r32) * GBK + slot]);
            acc[0][0] = __builtin_amdgcn_mfma_f32_32x32x16_f16(af0, bf0, acc[0][0], 0, 0, 0);
            acc[0][1] = __builtin_amdgcn_mfma_f32_32x32x16_f16(af0, bf1, acc[0][1], 0, 0, 0);
            acc[1][0] = __builtin_amdgcn_mfma_f32_32x32x16_f16(af1, bf0, acc[1][0], 0, 0, 0);
            acc[1][1] = __builtin_amdgcn_mfma_f32_32x32x16_f16(af1, bf1, acc[1][1], 0, 0, 0);
        }
        __syncthreads();
    }

    #pragma unroll
    for (int ib = 0; ib < 2; ++ib) {
        #pragma unroll
        for (int jb = 0; jb < 2; ++jb) {
            const size_t gn = n0 + wn + jb * 32 + r32;
            const float bb = bias[gn];
            #pragma unroll
            for (int r = 0; r < 16; ++r) {
                const size_t gm = m0 + wm + ib * 32 + (r & 3) + 8 * (r >> 2) + 4 * kg;
                float v = acc[ib][jb][r] + bb;
                float sl = v / (1.f + __expf(-v));
                out_h[gm * (size_t)N + gn] = (_Float16)sl;
            }
        }
    }
}

// ---------------------------------------------------------------------------
// GEMM2: 16x16x32 MFMA, m97 2-barrier 128x128 tile (0 conflicts),
// XCD-chunked.  out_f = C + bias + resid.   (byte-identical to r9)
// ---------------------------------------------------------------------------
template<int NCOLS>
__global__ __launch_bounds__(256)
void gemm2_16(const _Float16* __restrict__ A, const _Float16* __restrict__ W,
              const float* __restrict__ bias, const float* __restrict__ resid,
              float* __restrict__ out_f, int N, int K) {
    __shared__ _Float16 As[GBM * GBK];
    __shared__ _Float16 Bs[GBN * GBK];
    const int tid  = threadIdx.x;
    const int lane = tid & 63;
    const int wave = tid >> 6;
    const int wm = (wave >> 1) * 64;
    const int wn = (wave & 1) * 64;
    const int n  = blockIdx.y * gridDim.x + blockIdx.x;
    const int xc = n & 7, ii = n >> 3;
    const size_t m0 = (size_t)(xc + ((ii / NCOLS) << 3)) * GBM;
    const size_t n0 = (size_t)(ii % NCOLS) * GBN;
    const int fr = lane & 15;
    const int quad = lane >> 4;

    const int srow = wave * 32 + (lane >> 3);
    const int ccp  = ((lane & 7) ^ (lane >> 3)) * 8;
    const _Float16* ag = A + (m0 + srow) * (size_t)K + ccp;
    const _Float16* wg = W + (n0 + srow) * (size_t)K + ccp;
    _Float16* asl = &As[(wave * 32) * GBK];
    _Float16* bsl = &Bs[(wave * 32) * GBK];

    floatx4 acc[4][4] = {};

    for (int k0 = 0; k0 < K; k0 += GBK) {
        #pragma unroll
        for (int t = 0; t < 4; ++t) {
            load_lds16(ag + k0 + (size_t)(t * 8) * K, asl + t * 8 * GBK);
            load_lds16(wg + k0 + (size_t)(t * 8) * K, bsl + t * 8 * GBK);
        }
        __syncthreads();
        #pragma unroll
        for (int kk = 0; kk < GBK; kk += 32) {
            half8 af[4], bf[4];
            #pragma unroll
            for (int i = 0; i < 4; ++i) {
                const int slot = (((kk >> 3) + quad) ^ (fr & 7)) * 8;
                af[i] = *(const half8*)(&As[(wm + i * 16 + fr) * GBK + slot]);
                bf[i] = *(const half8*)(&Bs[(wn + i * 16 + fr) * GBK + slot]);
            }
            #pragma unroll
            for (int i = 0; i < 4; ++i)
                #pragma unroll
                for (int j = 0; j < 4; ++j)
                    acc[i][j] = __builtin_amdgcn_mfma_f32_16x16x32_f16(
                        af[i], bf[j], acc[i][j], 0, 0, 0);
        }
        __syncthreads();
    }

    #pragma unroll
    for (int i = 0; i < 4; ++i) {
        #pragma unroll
        for (int j = 0; j < 4; ++j) {
            #pragma unroll
            for (int r = 0; r < 4; ++r) {
                const size_t gm = m0 + wm + i * 16 + quad * 4 + r;
                const size_t gn = n0 + wn + j * 16 + fr;
                float v = acc[i][j][r] + bias[gn];
                out_f[gm * (size_t)N + gn] = v + resid[gm * (size_t)N + gn];
            }
        }
    }
}

extern "C" void kernel_launch(void* const* d_in, const int* in_sizes, int n_in,
                              void* d_out, int out_size, void* d_ws, size_t ws_size,
                              hipStream_t stream) {
    const float* x    = (const float*)d_in[0];
    const float* ln1w = (const float*)d_in[1];
    const float* ln1b = (const float*)d_in[2];
    const float* ln2w = (const float*)d_in[3];
    const float* ln2b = (const float*)d_in[4];
    const float* sc   = (const float*)d_in[5];
    const float* pre  = (const float*)d_in[6];
    const float* pim  = (const float*)d_in[7];
    const float* lre  = (const float*)d_in[8];
    const float* lim  = (const float*)d_in[9];
    const float* w1   = (const float*)d_in[10];
    const float* b1   = (const float*)d_in[11];
    const float* w2   = (const float*)d_in[12];
    const float* b2   = (const float*)d_in[13];

    char* ws = (char*)d_ws;
    float2*     st  = (float2*)(ws + ST_OFF);
    float2*     e   = (float2*)(ws + E_OFF);
    _Float16*   h2  = (_Float16*)(ws + H2_OFF);
    _Float16*   w1h = (_Float16*)(ws + W1H_OFF);
    _Float16*   w2h = (_Float16*)(ws + W2H_OFF);
    _Float16*   y1  = (_Float16*)(ws + Y1_OFF);
    float*      x2  = (float*)d_out;
    float*      outp = (float*)d_out;

    // blocks: 8192 stats + 4096 cast(w1) + 4096 cast(w2) = 16384
    prep<<<dim3(MROWS + 2 * CAST_BLKS), 256, 0, stream>>>(
        x, st, w1, w1h, w2, w2h);
    scan_partial<<<dim3(CHUNKS2, BATCH), 256, 0, stream>>>(
        x, st, ln1w, ln1b, pre, pim, e);
    scan_final<<<dim3(CHUNKS2, BATCH), 256, 0, stream>>>(
        x, st, ln1w, ln1b, ln2w, ln2b, pre, pim, sc, lre, lim, e, x2, h2);
    gemm1_32<32><<<dim3(FFD / GBN, MROWS / GBM), 256, 0, stream>>>(
        h2, w1h, b1, y1, FFD, DIMD);
    gemm2_16<8><<<dim3(DIMD / GBN, MROWS / GBM), 256, 0, stream>>>(
        y1, w2h, b2, x2, outp, DIMD, FFD);
}